// Round 3
// baseline (60560.468 us; speedup 1.0000x reference)
//
#include <hip/hip_runtime.h>
#include <hip/hip_cooperative_groups.h>
#include <math.h>

namespace cg = cooperative_groups;

// ---------------------------------------------------------------------------
// LSTMModel round 3: single persistent cooperative kernel for the whole
// T=256 recurrence. 256 blocks (1/CU) x 512 threads. Each CU owns 4
// h-indices (16 gate-cols), weights LDS-resident, c-state in registers,
// LN stats via device atomics + grid.sync (4 syncs/step).
// ---------------------------------------------------------------------------

#define N_   128
#define T_   256
#define QN_  16
#define INX  24
#define H_   1024
#define G4   4096
#define FDIM 768
#define EPS_ 1e-5f
#define K0_  1792
#define K1_  2048
#define W1OFF (16 * K0_)   // u16 offset of layer-1 weights in LDS

typedef unsigned short u16;
typedef __attribute__((ext_vector_type(8))) short bf16x8;
typedef __attribute__((ext_vector_type(4))) float f32x4;

__device__ __forceinline__ float sigmoidf_(float v) { return 1.0f / (1.0f + expf(-v)); }

__device__ __forceinline__ u16 f2bf(float f) {
  unsigned u = __float_as_uint(f);
  u += 0x7fffu + ((u >> 16) & 1u);
  return (u16)(u >> 16);
}

// ---- BatchNorm stats over the (N*T, 16) numeric block --------------------
__global__ __launch_bounds__(256) void bn_stats_k(const float* __restrict__ x,
    const float* __restrict__ gamma, const float* __restrict__ beta,
    float* __restrict__ scale, float* __restrict__ shift) {
  int q = blockIdx.x;
  int tid = threadIdx.x;
  float s = 0.f, s2 = 0.f;
  for (int r = tid; r < N_ * T_; r += 256) {
    float v = x[(size_t)r * INX + q];
    s += v; s2 += v * v;
  }
  for (int off = 32; off; off >>= 1) { s += __shfl_down(s, off); s2 += __shfl_down(s2, off); }
  __shared__ float red[2][4];
  int w = tid >> 6;
  if ((tid & 63) == 0) { red[0][w] = s; red[1][w] = s2; }
  __syncthreads();
  if (tid == 0) {
    float S = 0.f, S2 = 0.f;
    for (int i = 0; i < 4; ++i) { S += red[0][i]; S2 += red[1][i]; }
    float m   = S  / (float)(N_ * T_);
    float var = S2 / (float)(N_ * T_) - m * m;
    float rs  = rsqrtf(var + EPS_);
    scale[q] = rs * gamma[q];
    shift[q] = beta[q] - m * rs * gamma[q];
  }
}

// ---- Feature build for ALL steps: ft[t][n][768] bf16 ---------------------
__global__ __launch_bounds__(256) void feats_all_k(const float* __restrict__ x,
    const float* __restrict__ scale, const float* __restrict__ shift,
    const float* __restrict__ QnV, const float* __restrict__ QlV,
    u16* __restrict__ ft) {
  int rid = blockIdx.x;              // t*128 + n
  int t = rid >> 7, n = rid & 127;
  const float* xr = x + ((size_t)n * T_ + t) * INX;
  u16* frow = ft + (size_t)rid * FDIM;
  for (int f = threadIdx.x; f < FDIM; f += 256) {
    int d = f & 31;
    float v;
    if (f < 512) {
      int q = f >> 5;
      v = (xr[q] * scale[q] + shift[q]) * QnV[q * 32 + d];
    } else {
      int cg_ = (f - 512) >> 5;
      int idx = (int)xr[QN_ + cg_] + cg_ * 100;
      v = QlV[idx * 32 + d];
    }
    frow[f] = f2bf(v);
  }
}

// ---- Weight convert: W[k][col] fp32 -> WtP[(bcu*16+v)][k] bf16 -----------
// bcu = (col & 1023) >> 2 ; v = (col >> 10)*4 + (col & 3)
__global__ __launch_bounds__(256) void wconv_k(const float* __restrict__ W,
                                               u16* __restrict__ WtP, int K) {
  __shared__ u16 L[64][72];
  int tid = threadIdx.x;
  int k0 = blockIdx.x * 64, n0 = blockIdx.y * 64;
#pragma unroll
  for (int it = 0; it < 16; ++it) {
    int e = it * 256 + tid;
    int r = e >> 6, c = e & 63;
    L[r][c] = f2bf(W[(size_t)(k0 + r) * G4 + n0 + c]);
  }
  __syncthreads();
  int n = tid >> 2, ks = (tid & 3) << 4;
  int col = n0 + n;
  int bcu = (col & 1023) >> 2;
  int v   = (col >> 10) * 4 + (col & 3);
  u16* dst = WtP + ((size_t)(bcu * 16 + v)) * K + k0 + ks;
#pragma unroll
  for (int j = 0; j < 16; ++j) dst[j] = L[ks + j][n];
}

// ---- The persistent recurrence kernel ------------------------------------
__global__ __launch_bounds__(512, 2) void persist_k(
    const u16* __restrict__ WtP0, const u16* __restrict__ WtP1,
    const u16* __restrict__ ft,
    u16* __restrict__ h0, u16* __restrict__ h1,
    const float* __restrict__ b0, const float* __restrict__ b1,
    const float* __restrict__ lng, const float* __restrict__ lnb,
    const float* __restrict__ fcW, const float* __restrict__ fcb,
    float* __restrict__ stat0, float* __restrict__ stat1,
    float* __restrict__ logitb, float* __restrict__ out) {
  __shared__ u16 wlds[16 * K0_ + 16 * K1_];   // 120 KiB
  cg::grid_group grid = cg::this_grid();
  const int bcu  = blockIdx.x;
  const int tid  = threadIdx.x;
  const int wave = tid >> 6, lane = tid & 63;
  const int vcol = lane & 15, g = lane >> 4;
  const int gg = vcol >> 2, hh = vcol & 3;
  const int swz = vcol & 7;
  const int rowA  = wave * 16 + vcol;        // row this lane loads for A-frags
  const int rbase = wave * 16 + g * 4;       // acc rows rbase..rbase+3
  const int hidx  = bcu * 4 + hh;
  const int col0  = gg * 1024 + hidx;        // gates column

  // ---- one-time: weight slices global -> LDS (XOR chunk swizzle) ----
  for (int i = 0; i < 15; ++i) {
    int cid = tid + i * 512;                 // 7680 chunks total
    if (cid < 3584) {                        // layer 0: 16 vcols x 224 chunks
      int v = cid / 224, ck = cid - v * 224;
      *(bf16x8*)&wlds[v * K0_ + ((ck ^ (v & 7)) << 3)] =
          *(const bf16x8*)&WtP0[((size_t)(bcu * 16 + v)) * K0_ + (ck << 3)];
    } else {                                 // layer 1: 16 vcols x 256 chunks
      int c2 = cid - 3584;
      int v = c2 >> 8, ck = c2 & 255;
      *(bf16x8*)&wlds[W1OFF + v * K1_ + ((ck ^ (v & 7)) << 3)] =
          *(const bf16x8*)&WtP1[((size_t)(bcu * 16 + v)) * K1_ + (ck << 3)];
    }
  }
  __syncthreads();

  const float bias0v = b0[col0], bias1v = b1[col0];
  const float lng0v = lng[col0],      lnb0v = lnb[col0];
  const float lng1v = lng[G4 + col0], lnb1v = lnb[G4 + col0];
  const float fw0 = fcW[hidx * 2], fw1 = fcW[hidx * 2 + 1];

  float c0r[4] = {0.f, 0.f, 0.f, 0.f};
  float c1r[4] = {0.f, 0.f, 0.f, 0.f};

  const u16* paH0 = h0 + (size_t)rowA * H_ + g * 8;
  const u16* paH1 = h1 + (size_t)rowA * H_ + g * 8;
  const u16* wb0 = &wlds[vcol * K0_];
  const u16* wb1 = &wlds[W1OFF + vcol * K1_];

  for (int t = 0; t < T_; ++t) {
    // ================= phase 1: gemm0  (A = [h0 | ft_t], K=1792) =========
    const u16* paF = ft + ((size_t)t * N_ + rowA) * FDIM + g * 8;
    f32x4 acc = {0.f, 0.f, 0.f, 0.f};
    {
      bf16x8 a0, a1, bf0, bf1, an0, an1, bn0, bn1;
      a0  = *(const bf16x8*)(paH0);
      a1  = *(const bf16x8*)(paH0 + 32);
      bf0 = *(const bf16x8*)(wb0 + (((0 + g) ^ swz) << 3));
      bf1 = *(const bf16x8*)(wb0 + (((4 + g) ^ swz) << 3));
      for (int kc = 0; kc < 56; kc += 2) {
        int kn = kc + 2;
        if (kn < 56) {
          if (kn < 32) {
            an0 = *(const bf16x8*)(paH0 + kn * 32);
            an1 = *(const bf16x8*)(paH0 + (kn + 1) * 32);
          } else {
            an0 = *(const bf16x8*)(paF + (kn - 32) * 32);
            an1 = *(const bf16x8*)(paF + (kn - 31) * 32);
          }
          bn0 = *(const bf16x8*)(wb0 + ((((kn) * 4 + g) ^ swz) << 3));
          bn1 = *(const bf16x8*)(wb0 + ((((kn + 1) * 4 + g) ^ swz) << 3));
        }
        acc = __builtin_amdgcn_mfma_f32_16x16x32_bf16(a0, bf0, acc, 0, 0, 0);
        acc = __builtin_amdgcn_mfma_f32_16x16x32_bf16(a1, bf1, acc, 0, 0, 0);
        a0 = an0; a1 = an1; bf0 = bn0; bf1 = bn1;
      }
    }
    f32x4 accb0;
#pragma unroll
    for (int r = 0; r < 4; ++r) accb0[r] = acc[r] + bias0v;
#pragma unroll
    for (int r = 0; r < 4; ++r) {
      float s = accb0[r], q = s * s;
      s += __shfl_xor(s, 1); q += __shfl_xor(q, 1);
      s += __shfl_xor(s, 2); q += __shfl_xor(q, 2);
      if (hh == 0) {
        int idx = ((rbase + r) * 4 + gg) * 2;
        atomicAdd(&stat0[idx], s);
        atomicAdd(&stat0[idx + 1], q);
      }
    }
    grid.sync();

    // ================= phase 2: cell0 ====================================
    if (bcu == 0)
      for (int i = tid; i < 2048; i += 512) stat1[i] = 0.f;
    if (t > 0 && bcu < N_ && tid == 0) {      // softmax for step t-1
      int p1 = (t - 1) & 1;
      float L0 = logitb[p1 * 256 + bcu * 2]     + fcb[0];
      float L1 = logitb[p1 * 256 + bcu * 2 + 1] + fcb[1];
      float mx = fmaxf(L0, L1);
      float e0 = expf(L0 - mx), e1 = expf(L1 - mx);
      float inv = 1.f / (e0 + e1);
      out[((size_t)bcu * T_ + (t - 1)) * 2]     = e0 * inv;
      out[((size_t)bcu * T_ + (t - 1)) * 2 + 1] = e1 * inv;
      logitb[p1 * 256 + bcu * 2] = 0.f;
      logitb[p1 * 256 + bcu * 2 + 1] = 0.f;
    }
#pragma unroll
    for (int r = 0; r < 4; ++r) {
      int srow = rbase + r;
      float sum = stat0[(srow * 4 + gg) * 2];
      float sq  = stat0[(srow * 4 + gg) * 2 + 1];
      float mean = sum * (1.f / H_);
      float var  = sq * (1.f / H_) - mean * mean;
      float rstd = rsqrtf(var + EPS_);
      float nv = (accb0[r] - mean) * rstd * lng0v + lnb0v;
      float a4 = __shfl_xor(nv, 4), a8 = __shfl_xor(nv, 8), a12 = __shfl_xor(nv, 12);
      float vi = (gg == 0) ? nv  : (gg == 1) ? a4  : (gg == 2) ? a8  : a12;
      float vf = (gg == 0) ? a4  : (gg == 1) ? nv  : (gg == 2) ? a12 : a8;
      float vg = (gg == 0) ? a8  : (gg == 1) ? a12 : (gg == 2) ? nv  : a4;
      float vo = (gg == 0) ? a12 : (gg == 1) ? a8  : (gg == 2) ? a4  : nv;
      float ig = sigmoidf_(vi), fg = sigmoidf_(vf), og = sigmoidf_(vo);
      float cn = c0r[r] * fg + ig * tanhf(vg);
      float xn = og * tanhf(cn) + vg;
      c0r[r] = cn;
      if (gg == 0) h0[(size_t)srow * H_ + hidx] = f2bf(xn);
    }
    grid.sync();

    // ================= phase 3: gemm1  (A = [h1 | h0new], K=2048) ========
    f32x4 acc1 = {0.f, 0.f, 0.f, 0.f};
    {
      bf16x8 a0, a1, bf0, bf1, an0, an1, bn0, bn1;
      a0  = *(const bf16x8*)(paH1);
      a1  = *(const bf16x8*)(paH1 + 32);
      bf0 = *(const bf16x8*)(wb1 + (((0 + g) ^ swz) << 3));
      bf1 = *(const bf16x8*)(wb1 + (((4 + g) ^ swz) << 3));
      for (int kc = 0; kc < 64; kc += 2) {
        int kn = kc + 2;
        if (kn < 64) {
          if (kn < 32) {
            an0 = *(const bf16x8*)(paH1 + kn * 32);
            an1 = *(const bf16x8*)(paH1 + (kn + 1) * 32);
          } else {
            an0 = *(const bf16x8*)(paH0 + (kn - 32) * 32);
            an1 = *(const bf16x8*)(paH0 + (kn - 31) * 32);
          }
          bn0 = *(const bf16x8*)(wb1 + ((((kn) * 4 + g) ^ swz) << 3));
          bn1 = *(const bf16x8*)(wb1 + ((((kn + 1) * 4 + g) ^ swz) << 3));
        }
        acc1 = __builtin_amdgcn_mfma_f32_16x16x32_bf16(a0, bf0, acc1, 0, 0, 0);
        acc1 = __builtin_amdgcn_mfma_f32_16x16x32_bf16(a1, bf1, acc1, 0, 0, 0);
        a0 = an0; a1 = an1; bf0 = bn0; bf1 = bn1;
      }
    }
    f32x4 accb1;
#pragma unroll
    for (int r = 0; r < 4; ++r) accb1[r] = acc1[r] + bias1v;
#pragma unroll
    for (int r = 0; r < 4; ++r) {
      float s = accb1[r], q = s * s;
      s += __shfl_xor(s, 1); q += __shfl_xor(q, 1);
      s += __shfl_xor(s, 2); q += __shfl_xor(q, 2);
      if (hh == 0) {
        int idx = ((rbase + r) * 4 + gg) * 2;
        atomicAdd(&stat1[idx], s);
        atomicAdd(&stat1[idx + 1], q);
      }
    }
    grid.sync();

    // ================= phase 4: cell1 (+logits) ==========================
    if (bcu == 0)
      for (int i = tid; i < 2048; i += 512) stat0[i] = 0.f;
    int p = t & 1;
#pragma unroll
    for (int r = 0; r < 4; ++r) {
      int srow = rbase + r;
      float sum = stat1[(srow * 4 + gg) * 2];
      float sq  = stat1[(srow * 4 + gg) * 2 + 1];
      float mean = sum * (1.f / H_);
      float var  = sq * (1.f / H_) - mean * mean;
      float rstd = rsqrtf(var + EPS_);
      float nv = (accb1[r] - mean) * rstd * lng1v + lnb1v;
      float a4 = __shfl_xor(nv, 4), a8 = __shfl_xor(nv, 8), a12 = __shfl_xor(nv, 12);
      float vi = (gg == 0) ? nv  : (gg == 1) ? a4  : (gg == 2) ? a8  : a12;
      float vf = (gg == 0) ? a4  : (gg == 1) ? nv  : (gg == 2) ? a12 : a8;
      float vg = (gg == 0) ? a8  : (gg == 1) ? a12 : (gg == 2) ? nv  : a4;
      float vo = (gg == 0) ? a12 : (gg == 1) ? a8  : (gg == 2) ? a4  : nv;
      float ig = sigmoidf_(vi), fg = sigmoidf_(vf), og = sigmoidf_(vo);
      float cn = c1r[r] * fg + ig * tanhf(vg);
      float xn = og * tanhf(cn) + vg;
      c1r[r] = cn;
      if (gg == 0) h1[(size_t)srow * H_ + hidx] = f2bf(xn);
      float cl0 = xn * fw0, cl1 = xn * fw1;
      cl0 += __shfl_xor(cl0, 1); cl1 += __shfl_xor(cl1, 1);
      cl0 += __shfl_xor(cl0, 2); cl1 += __shfl_xor(cl1, 2);
      if (vcol == 0) {
        atomicAdd(&logitb[p * 256 + srow * 2], cl0);
        atomicAdd(&logitb[p * 256 + srow * 2 + 1], cl1);
      }
    }
    grid.sync();
  }

  // tail: softmax for t = T-1
  if (bcu < N_ && tid == 0) {
    int p1 = (T_ - 1) & 1;
    float L0 = logitb[p1 * 256 + bcu * 2]     + fcb[0];
    float L1 = logitb[p1 * 256 + bcu * 2 + 1] + fcb[1];
    float mx = fmaxf(L0, L1);
    float e0 = expf(L0 - mx), e1 = expf(L1 - mx);
    float inv = 1.f / (e0 + e1);
    out[((size_t)bcu * T_ + (T_ - 1)) * 2]     = e0 * inv;
    out[((size_t)bcu * T_ + (T_ - 1)) * 2 + 1] = e1 * inv;
  }
}

// ---------------------------------------------------------------------------
extern "C" void kernel_launch(void* const* d_in, const int* in_sizes, int n_in,
                              void* d_out, int out_size, void* d_ws, size_t ws_size,
                              hipStream_t stream) {
  const float* x   = (const float*)d_in[0];
  const float* QnV = (const float*)d_in[1];
  const float* QlV = (const float*)d_in[2];
  const float* bng = (const float*)d_in[3];
  const float* bnb = (const float*)d_in[4];
  const float* W0  = (const float*)d_in[5];
  const float* b0  = (const float*)d_in[6];
  const float* W1  = (const float*)d_in[7];
  const float* b1  = (const float*)d_in[8];
  const float* lng = (const float*)d_in[9];
  const float* lnb = (const float*)d_in[10];
  const float* fcW = (const float*)d_in[11];
  const float* fcb = (const float*)d_in[12];
  float* out = (float*)d_out;

  float* scale  = (float*)d_ws;                    // 64
  float* shift  = scale + 64;                      // 64
  float* stat0  = shift + 64;                      // 2048
  float* stat1  = stat0 + 2048;                    // 2048
  float* logitb = stat1 + 2048;                    // 512
  u16* h0   = (u16*)(logitb + 512);
  u16* h1   = h0 + (size_t)N_ * H_;
  u16* ft   = h1 + (size_t)N_ * H_;                // 256*128*768
  u16* WtP0 = ft + (size_t)N_ * T_ * FDIM;         // 4096*1792
  u16* WtP1 = WtP0 + (size_t)G4 * K0_;             // 4096*2048

  hipMemsetAsync(h0, 0, (size_t)2 * N_ * H_ * sizeof(u16), stream);
  hipMemsetAsync(stat0, 0, 2048 * sizeof(float), stream);
  hipMemsetAsync(logitb, 0, 512 * sizeof(float), stream);

  bn_stats_k<<<QN_, 256, 0, stream>>>(x, bng, bnb, scale, shift);
  feats_all_k<<<N_ * T_, 256, 0, stream>>>(x, scale, shift, QnV, QlV, ft);
  wconv_k<<<dim3(K0_ / 64, G4 / 64), 256, 0, stream>>>(W0, WtP0, K0_);
  wconv_k<<<dim3(K1_ / 64, G4 / 64), 256, 0, stream>>>(W1, WtP1, K1_);

  void* args[] = {
    (void*)&WtP0, (void*)&WtP1, (void*)&ft, (void*)&h0, (void*)&h1,
    (void*)&b0, (void*)&b1, (void*)&lng, (void*)&lnb,
    (void*)&fcW, (void*)&fcb, (void*)&stat0, (void*)&stat1,
    (void*)&logitb, (void*)&out
  };
  hipLaunchCooperativeKernel((void*)persist_k, dim3(256), dim3(512), args, 0, stream);
}